// Round 10
// baseline (6621.799 us; speedup 1.0000x reference)
//
#include <hip/hip_runtime.h>
#include <math.h>

// Archetipes RNN scan: T=256 sequential steps, M=16 modules, H=256, I=128.
// R10: tagged 2-slot ring = "data is the flag", HOT edition.
// Evidence trail: R9 killed the poller-count theory (16x fewer pollers,
// same time). R8 killed per-step slots (cold-line polls -> FETCH +212 MB
// of HBM-latency sweeps). R7/R9's 9 us/step = 3 serialized fabric hops:
// publish drain (vmcnt0 ack) -> release flag visibility -> staging fetch.
// This round removes ALL THREE: producer emits 16 independent relaxed
// agent u64 stores (value<<32 | epoch tag); consumers poll their OWN 4
// tagged words (detect == data in hand). Ring = 2 slots x 32 KB, lines
// permanently MALL-hot -> no cold misses (R8's poison).
// Ring safety (no ack needed): overwriting slot t&1 with epoch t+2
// requires consuming all tags of t+1 => every block passed sync(t) =>
// all reads of epoch t complete. Causality flows through tag values.
// Replay safety: exact-match monotone tags (g_epoch += T by block 0 at
// end; T even keeps slot parity); final step NOT published so next
// launch's zero-publish (tag base+T) can't collide with stale data.
// Weights register/AGPR-resident (R3). hy/hz/fb all buffered in LDS
// (81 KB, 1 block/CU), single scattered flush after the loop.
// ONE __syncthreads per step; no other sync primitives anywhere.

#define DT_C    0.042f
#define GAMMA_C 2.7f
#define EPS_C   4.7f

constexpr int M = 16, H = 256, I = 128, T = 256;
constexpr int NROW = M * H;   // 4096
constexpr int NBLK = 256;
constexpr int NTHR = 1024;    // 16 waves

typedef float f32x4 __attribute__((ext_vector_type(4)));
typedef unsigned long long u64;

// 2-slot tagged ring, layout [slot][h][m] (16 u64 = 128 B per (slot,h)).
// 64 KB total -> permanently LLC-resident. Zero-init: tag 0 = first
// launch's base, value 0 = correct initial state.
__device__ __align__(64) u64 g_ring[2 * NROW];
__device__ unsigned int g_epoch;

__device__ __forceinline__ u64 pack(float v, unsigned int tag) {
  return ((u64)__float_as_uint(v) << 32) | (u64)tag;
}

__global__ __launch_bounds__(NTHR) void rnn_persistent(
    const float* __restrict__ x,      // T*I
    const float* __restrict__ wm,     // M*M*H*H
    const float* __restrict__ conn,   // M*M
    const float* __restrict__ mask,   // M
    const float* __restrict__ W_in,   // M*H*I
    const float* __restrict__ W_rec,  // M*H*H
    const float* __restrict__ bias,   // M*H
    float* __restrict__ out)          // T*M*2*H state_seq, then T*M*H fb_seq
{
  const int h    = blockIdx.x;
  const int tid  = threadIdx.x;
  const int m    = tid >> 6;      // wave = module
  const int lane = tid & 63;

  __shared__ float hy_lds[2][NROW];     // 32 KB, [buf][m][h]
  __shared__ float outb_hy[T][M];       // 16 KB
  __shared__ float outb_hz[T][M];       // 16 KB
  __shared__ float outb_fb[T][M];       // 16 KB
  __shared__ float s_c[M * M];
  __shared__ float s_scal[M];
  __shared__ int   s_olist[M][M];
  __shared__ float s_oc[M][M];
  __shared__ int   s_ocnt[M];
  __shared__ unsigned int s_base;

  if (tid == 0)
    s_base = __hip_atomic_load(&g_epoch, __ATOMIC_RELAXED, __HIP_MEMORY_SCOPE_AGENT);
  if (tid < M * M) s_c[tid] = conn[tid];
  __syncthreads();
  if (tid < M) {
    float s = 0.f; int cnt = 0;
    for (int o = 0; o < M; ++o) {
      float c = s_c[tid * M + o];
      s += c;
      if (c != 0.f) { s_olist[tid][cnt] = o; s_oc[tid][cnt] = c; ++cnt; }
    }
    for (int k = cnt; k < M; ++k) { s_olist[tid][k] = 0; s_oc[tid][k] = 0.f; }
    s_ocnt[tid] = cnt;
    s_scal[tid] = 1.0f / fmaxf(s, 1.0f);
  }
  __syncthreads();

  const int   row   = m * H + h;
  const float maskm = mask[m];
  const float biasv = bias[row];
  const float scal  = s_scal[m];
  const int   ocnt  = s_ocnt[m];
  const unsigned int base = s_base;   // even (T=256 per launch)

  // ---- publish initial state: zeros tagged base into slot 0 ----
  // No drain needed: consumers self-synchronize on the tags.
  if (tid < M)
    __hip_atomic_store(&g_ring[h * M + tid], pack(0.0f, base),
                       __ATOMIC_RELAXED, __HIP_MEMORY_SCOPE_AGENT);
  float hz = 0.f;

  // ---- one-time: weights into registers (conn pre-applied) ----
  f32x4 wreg[M];
#pragma unroll
  for (int k = 0; k < M; ++k) {
    if (k < ocnt) {
      const int o = s_olist[m][k];
      const f32x4 wv = *reinterpret_cast<const f32x4*>(
          wm + ((size_t)(m * M + o) * H + h) * H + 4 * lane);
      wreg[k] = wv * s_oc[m][k];
    } else {
      wreg[k] = (f32x4)0.f;
    }
  }
  const f32x4  wrec = *reinterpret_cast<const f32x4*>(W_rec + (size_t)row * H + 4 * lane);
  const float2 win  = *reinterpret_cast<const float2*>(W_in + (size_t)row * I + 2 * lane);

  // x[0] prefetch (per-lane slice; same for every wave)
  float2 xd = *reinterpret_cast<const float2*>(x + 2 * lane);

  const int hcol = tid & 255;           // column this thread stages
  const int m0   = (tid >> 8) << 2;     // its 4 modules of that column

  for (int t = 0; t < T; ++t) {
    const bool last = (t == T - 1);
    const int  cur  = t & 1;            // ring slot == LDS buf index

    // ---- poll own 4 tagged words of slot t&1; match => data in hand ----
    {
      const unsigned int tgt = base + (unsigned int)t;
      const u64* src = g_ring + (size_t)cur * NROW + hcol * M + m0;
      u64 v0, v1, v2, v3;
      for (;;) {
        v0 = __hip_atomic_load(src + 0, __ATOMIC_RELAXED, __HIP_MEMORY_SCOPE_AGENT);
        v1 = __hip_atomic_load(src + 1, __ATOMIC_RELAXED, __HIP_MEMORY_SCOPE_AGENT);
        v2 = __hip_atomic_load(src + 2, __ATOMIC_RELAXED, __HIP_MEMORY_SCOPE_AGENT);
        v3 = __hip_atomic_load(src + 3, __ATOMIC_RELAXED, __HIP_MEMORY_SCOPE_AGENT);
        if (((unsigned int)v0 == tgt) & ((unsigned int)v1 == tgt) &
            ((unsigned int)v2 == tgt) & ((unsigned int)v3 == tgt)) break;
        __builtin_amdgcn_s_sleep(1);
      }
      // transpose into LDS[m][h]; wave-stride-1 columns -> 2-way banks (free)
      hy_lds[cur][(m0 + 0) * H + hcol] = __uint_as_float((unsigned int)(v0 >> 32));
      hy_lds[cur][(m0 + 1) * H + hcol] = __uint_as_float((unsigned int)(v1 >> 32));
      hy_lds[cur][(m0 + 2) * H + hcol] = __uint_as_float((unsigned int)(v2 >> 32));
      hy_lds[cur][(m0 + 3) * H + hcol] = __uint_as_float((unsigned int)(v3 >> 32));
    }
    __syncthreads();   // the ONLY barrier per step

    // input term (xd prefetched last iteration)
    float acc_o = win.x * (maskm * xd.x);
    acc_o = fmaf(win.y, maskm * xd.y, acc_o);
    // recurrent term
    {
      const f32x4 hp = *reinterpret_cast<const f32x4*>(&hy_lds[cur][m * H + 4 * lane]);
      acc_o = fmaf(wrec.x, hp.x, acc_o);
      acc_o = fmaf(wrec.y, hp.y, acc_o);
      acc_o = fmaf(wrec.z, hp.z, acc_o);
      acc_o = fmaf(wrec.w, hp.w, acc_o);
    }
    // feedback: register weights x LDS hy fragments
    float acc_fb = 0.f;
#pragma unroll
    for (int k = 0; k < M; ++k) {
      if (k < ocnt) {
        const int o = s_olist[m][k];
        const f32x4 hp = *reinterpret_cast<const f32x4*>(&hy_lds[cur][o * H + 4 * lane]);
        float po = wreg[k].x * hp.x;
        po = fmaf(wreg[k].y, hp.y, po);
        po = fmaf(wreg[k].z, hp.z, po);
        po = fmaf(wreg[k].w, hp.w, po);
        acc_fb += po;
      }
    }

    // wave-wide butterfly reduce
    for (int off = 32; off > 0; off >>= 1) {
      acc_fb += __shfl_xor(acc_fb, off);
      acc_o  += __shfl_xor(acc_o,  off);
    }

    if (lane == 0) {
      const float fb   = scal * acc_fb;
      const float hy_p = hy_lds[cur][m * H + h];
      const float pre  = acc_o + biasv + fb;
      const float hz_n = hz + DT_C * (tanhf(pre) - GAMMA_C * hy_p - EPS_C * hz);
      const float hy_n = hy_p + DT_C * hz_n;
      hz = hz_n;
      // publish epoch base+t+1 into slot (t+1)&1 — one tagged u64,
      // no drain, no flag, no barrier. Skip on last step (ring hygiene
      // for the next launch's zero-publish with tag base+T).
      if (!last)
        __hip_atomic_store(&g_ring[(size_t)((t + 1) & 1) * NROW + h * M + m],
                           pack(hy_n, base + (unsigned int)t + 1u),
                           __ATOMIC_RELAXED, __HIP_MEMORY_SCOPE_AGENT);
      outb_hy[t][m] = hy_n;
      outb_hz[t][m] = hz_n;
      outb_fb[t][m] = fb;
    }

    if (!last)
      xd = *reinterpret_cast<const float2*>(x + (size_t)(t + 1) * I + 2 * lane);
  }

  __syncthreads();   // outb_* complete

  // ---- one-time flush from LDS ----
  const size_t fb_base = (size_t)T * M * 2 * H;
  for (int i = tid; i < T * M; i += NTHR) {
    const int t  = i >> 4;
    const int mm = i & 15;
    const size_t so = (size_t)t * (M * 2 * H) + (size_t)mm * (2 * H);
    out[so + h]     = outb_hy[t][mm];
    out[so + H + h] = outb_hz[t][mm];
    out[fb_base + (size_t)t * (M * H) + (size_t)mm * H + h] = outb_fb[t][mm];
  }

  // ---- advance epoch once per launch ----
  if (h == 0 && tid == 0)
    __hip_atomic_fetch_add(&g_epoch, (unsigned int)T, __ATOMIC_ACQ_REL,
                           __HIP_MEMORY_SCOPE_AGENT);
}

extern "C" void kernel_launch(void* const* d_in, const int* in_sizes, int n_in,
                              void* d_out, int out_size, void* d_ws, size_t ws_size,
                              hipStream_t stream) {
  const float* x     = (const float*)d_in[0];
  const float* wm    = (const float*)d_in[1];
  const float* conn  = (const float*)d_in[2];
  const float* mask  = (const float*)d_in[3];
  const float* W_in  = (const float*)d_in[4];
  const float* W_rec = (const float*)d_in[5];
  const float* bias  = (const float*)d_in[6];

  rnn_persistent<<<NBLK, NTHR, 0, stream>>>(
      x, wm, conn, mask, W_in, W_rec, bias, (float*)d_out);
}